// Round 10
// baseline (230.605 us; speedup 1.0000x reference)
//
#include <hip/hip_runtime.h>
#include <hip/hip_bf16.h>

#define BB   256
#define II   1152
#define OO   10
#define DOUT 16
#define NIB  32        // i-chunks / s_partial planes
#define PCH  20        // LDS chunk stride per (o,dsub): dsub*20 mod 32 -> conflict-free b128 reads

// Pass kernel, barrier-free waves: each wave owns 8 batches x 9 i's and a
// PRIVATE LDS w-tile (stage -> read within the same wave; DS program order
// replaces __syncthreads -- zero barriers in the hot loop). Register prefetch
// (pre[10]) pipelines next w-row global loads behind compute. 1024 blocks
// (32 ic fast => XCD-local w, x 32 bgrp) x 4 waves = 16 waves/CU: DS and VALU
// of different waves overlap. Lane = bl*8 + dsub (batch, d-pair).
template<int K>
__global__ __launch_bounds__(256, 4) void pass_kernel(
    const float* __restrict__ x,   // fp32 [B][I][8]
    const float* __restrict__ w,   // fp32 [O][I][16][8]
    const float* __restrict__ V,   // fp32 [B][O][16]
    float* __restrict__ sp)        // fp32 [NIB][B][O][16]
{
  const int tid  = threadIdx.x;
  const int lane = tid & 63;
  const int wv   = tid >> 6;           // i-quarter within the chunk
  const int dsub = lane & 7;           // d-pair index
  const int bl   = lane >> 3;          // batch-in-wave (8)
  const int ic   = blockIdx.x & 31;    // i-chunk, fast-varying => XCD-local w
  const int bgrp = blockIdx.x >> 5;    // 8-batch group
  const int b    = bgrp * 8 + bl;
  const int i0   = ic * 36 + wv * 9;

  __shared__ float smem[4][OO * 8 * PCH];   // 4 private tiles, 25.6 KB total
  float* wt = smem[wv];

  float Vr[OO][2];
  if (K >= 1) {
#pragma unroll
    for (int o = 0; o < OO; ++o) {
      const float2 v2 = *(const float2*)(V + (b * OO + o) * DOUT + dsub * 2);
      Vr[o][0] = v2.x; Vr[o][1] = v2.y;
    }
  }

  float s[OO][2];
#pragma unroll
  for (int o = 0; o < OO; ++o) { s[o][0] = 0.f; s[o][1] = 0.f; }

  // staging map: 64 lanes x float2 cover one o-row (128 floats) per round
  const int so2 = lane * 2;
  const int sds = so2 >> 4, ssk = so2 & 15;

  float2 pre[OO];
#pragma unroll
  for (int o = 0; o < OO; ++o)
    pre[o] = *(const float2*)(w + ((size_t)o * II + i0) * 128 + so2);

#pragma unroll 1
  for (int ii = 0; ii < 9; ++ii) {
    const int i = i0 + ii;
    // park prefetched w-row into this wave's private tile (same-wave RAW via lgkmcnt)
#pragma unroll
    for (int o = 0; o < OO; ++o)
      *(float2*)&wt[(o * 8 + sds) * PCH + ssk] = pre[o];
    if (ii < 8) {
#pragma unroll
      for (int o = 0; o < OO; ++o)
        pre[o] = *(const float2*)(w + ((size_t)o * II + i + 1) * 128 + so2);
    }

    const float* xp = x + ((size_t)b * II + i) * 8;
    const float4 x0 = *(const float4*)(xp);
    const float4 x1 = *(const float4*)(xp + 4);

    float xh[OO][2];
    float t[OO];
#pragma unroll 2
    for (int o = 0; o < OO; ++o) {
      const float4* wp = (const float4*)(wt + (o * 8 + dsub) * PCH);
      const float4 wa = wp[0], wb2 = wp[1], wc = wp[2], wd = wp[3];
      xh[o][0] = wa.x * x0.x + wa.y * x0.y + wa.z * x0.z + wa.w * x0.w
               + wb2.x * x1.x + wb2.y * x1.y + wb2.z * x1.z + wb2.w * x1.w;
      xh[o][1] = wc.x * x0.x + wc.y * x0.y + wc.z * x0.z + wc.w * x0.w
               + wd.x * x1.x + wd.y * x1.y + wd.z * x1.z + wd.w * x1.w;
      if (K >= 1)
        t[o] = Vr[o][0] * xh[o][0] + Vr[o][1] * xh[o][1];
    }

    if (K == 0) {
#pragma unroll
      for (int o = 0; o < OO; ++o) { s[o][0] += xh[o][0]; s[o][1] += xh[o][1]; }
    } else {
#pragma unroll
      for (int o = 0; o < OO; ++o) {     // reduce over the 8 dsub lanes
        t[o] += __shfl_xor(t[o], 1);
        t[o] += __shfl_xor(t[o], 2);
        t[o] += __shfl_xor(t[o], 4);
      }
      float sum = 0.f;
#pragma unroll
      for (int o = 0; o < OO; ++o) { t[o] = __expf(t[o]); sum += t[o]; }
      const float inv = __builtin_amdgcn_rcpf(sum);  // |t|<1 pre-exp; 1-ulp ok
#pragma unroll
      for (int o = 0; o < OO; ++o) {
        const float c = t[o] * inv;
        s[o][0] += c * xh[o][0];
        s[o][1] += c * xh[o][1];
      }
    }
  }

  if (K == 0) {
#pragma unroll
    for (int o = 0; o < OO; ++o) { s[o][0] *= 0.1f; s[o][1] *= 0.1f; }
  }

  // Cross-wave reduce over the 4 i-quarters, reusing each wave's own dead tile
  // (own region -> no barrier needed before the writes).
  if (wv > 0) {
#pragma unroll
    for (int o = 0; o < OO; ++o) {
      wt[bl * 160 + o * 16 + dsub * 2]     = s[o][0];
      wt[bl * 160 + o * 16 + dsub * 2 + 1] = s[o][1];
    }
  }
  __syncthreads();
  if (wv == 0) {
    float* out = sp + ((size_t)ic * BB + b) * (OO * DOUT);
#pragma unroll
    for (int o = 0; o < OO; ++o) {
      const int k = bl * 160 + o * 16 + dsub * 2;
      out[o * 16 + dsub * 2]     = s[o][0] + smem[1][k] + smem[2][k] + smem[3][k];
      out[o * 16 + dsub * 2 + 1] = s[o][1] + smem[1][k + 1] + smem[2][k + 1] + smem[3][k + 1];
    }
  }
}

// Combine partials over NIB i-planes, squash, update V / write final output.
template<int K>
__global__ __launch_bounds__(256) void reduce_kernel(
    const float* __restrict__ s_partial,   // [NIB][B*O*DOUT]
    float* __restrict__ V,                 // [B*O*DOUT]
    float* __restrict__ out)               // fp32 [B*O*DOUT]
{
  const int idx = blockIdx.x * 256 + threadIdx.x;    // over B*O*DOUT = 40960
  float s = 0.f;
#pragma unroll
  for (int ib = 0; ib < NIB; ++ib)
    s += s_partial[(size_t)ib * (BB * OO * DOUT) + idx];

  // squash over the 16 Dout lanes (contiguous 16-lane groups share (b,o))
  float sq = s * s;
  sq += __shfl_xor(sq, 1);
  sq += __shfl_xor(sq, 2);
  sq += __shfl_xor(sq, 4);
  sq += __shfl_xor(sq, 8);
  const float mag = sqrtf(sq);
  const float v = sq / (1.f + sq) * (s / (mag + 1e-8f));

  if (K == 0)      V[idx] = v;
  else if (K == 1) V[idx] += v;
  else             out[idx] = v;
}

extern "C" void kernel_launch(void* const* d_in, const int* in_sizes, int n_in,
                              void* d_out, int out_size, void* d_ws, size_t ws_size,
                              hipStream_t stream) {
  const float* x = (const float*)d_in[0];   // fp32 [256,1152,8]
  const float* w = (const float*)d_in[1];   // fp32 [10,1152,16,8]
  float* out = (float*)d_out;               // fp32 [256,10,16]

  float* s_partial = (float*)d_ws;                             // NIB*B*O*DOUT floats (5.2 MB)
  float* V = s_partial + (size_t)NIB * BB * OO * DOUT;         // B*O*DOUT floats

  const int pg = 1024;                      // 32 ic (fast) x 32 bgrp; 4 blocks/CU
  const int rg = (BB * OO * DOUT) / 256;    // 160 blocks

  pass_kernel<0><<<pg, 256, 0, stream>>>(x, w, V, s_partial);
  reduce_kernel<0><<<rg, 256, 0, stream>>>(s_partial, V, out);
  pass_kernel<1><<<pg, 256, 0, stream>>>(x, w, V, s_partial);
  reduce_kernel<1><<<rg, 256, 0, stream>>>(s_partial, V, out);
  pass_kernel<2><<<pg, 256, 0, stream>>>(x, w, V, s_partial);
  reduce_kernel<2><<<rg, 256, 0, stream>>>(s_partial, V, out);
}

// Round 11
// 226.840 us; speedup vs baseline: 1.0166x; 1.0166x over previous
//
#include <hip/hip_runtime.h>
#include <hip/hip_bf16.h>

#define BB   256
#define II   1152
#define OO   10
#define DOUT 16
#define NIC  64        // i-chunks (18 i each)
#define PCH  20        // LDS chunk stride per (o,dsub): dsub*20 mod 32 -> conflict-free b128 reads

// Cross-lane reduce helpers: xor1/xor2 on the VALU pipe (DPP quad_perm),
// xor4 on DS (ds_swizzle). Shifts 2/3 of the t-reduction off the binding
// DS pipe (R9 post-mortem: DS-issue bound).
__device__ __forceinline__ float dpp_add_xor1(float v) {
  int r = __builtin_amdgcn_mov_dpp(__float_as_int(v), 0xB1, 0xF, 0xF, true);
  return v + __int_as_float(r);
}
__device__ __forceinline__ float dpp_add_xor2(float v) {
  int r = __builtin_amdgcn_mov_dpp(__float_as_int(v), 0x4E, 0xF, 0xF, true);
  return v + __int_as_float(r);
}
__device__ __forceinline__ float swz_add_xor4(float v) {
  int r = __builtin_amdgcn_ds_swizzle(__float_as_int(v), 0x101F);
  return v + __int_as_float(r);
}

// Pass kernel (R9 skeleton): w staged global->LDS (coalesced float2),
// conflict-free broadcast reads. Lane = bl*8 + dsub (batch, d-pair).
// Block = 4 waves = 2 bh x 2 ih over 16 batches x 18 i. 64 ic-chunks
// (fast-varying => XCD-local w) x 16 bg = 1024 blocks = 4 blocks/CU =
// 16 waves/CU for cross-wave DS/VALU overlap. Epilogue: block-reduced s
// accumulated into a single global plane via unsafeAtomicAdd.
template<int K>
__global__ __launch_bounds__(256, 4) void pass_kernel(
    const float* __restrict__ x,     // fp32 [B][I][8]
    const float* __restrict__ w,     // fp32 [O][I][16][8]
    const float* __restrict__ V,     // fp32 [B][O][16]
    float* __restrict__ plane)       // fp32 [B][O][16] accumulator (pre-zeroed)
{
  const int tid  = threadIdx.x;
  const int lane = tid & 63;
  const int wv   = tid >> 6;
  const int bh   = wv & 1;             // b-half of the block's 16 batches
  const int ih   = wv >> 1;            // i-half (9 i each)
  const int dsub = lane & 7;           // d-pair index (d = 2*dsub + dlo)
  const int bl   = lane >> 3;          // batch-in-wave (8)
  const int ic   = blockIdx.x & 63;    // i-chunk, fast-varying => XCD-local w
  const int bg   = blockIdx.x >> 6;    // 16 batches per block
  const int b    = bg * 16 + bh * 8 + bl;
  const int i0   = ic * 18 + ih * 9;

  __shared__ float wt[2][2][OO * 8 * PCH];   // [ih][buf][1600] = 25.6 KB
  __shared__ float red[16][168];             // cross-ih reduce, padded rows

  float Vr[OO][2];
  if (K >= 1) {
#pragma unroll
    for (int o = 0; o < OO; ++o) {
      const float2 v2 = *(const float2*)(V + (b * OO + o) * DOUT + dsub * 2);
      Vr[o][0] = v2.x; Vr[o][1] = v2.y;
    }
  }

  float s[OO][2];
#pragma unroll
  for (int o = 0; o < OO; ++o) { s[o][0] = 0.f; s[o][1] = 0.f; }

  // staging: 128 lanes (this i-half's wave pair) load w row i (1280 floats)
  // as float2: per 2-o group one coalesced 512 B load per wave.
  const int p    = bh * 64 + lane;       // 0..127
  const int so   = p >> 6;               // o parity (== bh)
  const int idx2 = (p & 63) * 2;         // even element within o-row
  const int sds  = idx2 >> 4;            // dsub 0..7
  const int ssk  = idx2 & 15;            // 0,2,..,14

  #define STAGE(i, buf)                                                        \
    {                                                                          \
      _Pragma("unroll")                                                        \
      for (int og = 0; og < 5; ++og) {                                         \
        const int o = og * 2 + so;                                             \
        const float2 v2 = *(const float2*)(w + ((size_t)o * II + (i)) * (DOUT * DIN_) + idx2); \
        *(float2*)&wt[ih][buf][(o * 8 + sds) * PCH + ssk] = v2;                \
      }                                                                        \
    }
  #define DIN_ 8

  STAGE(i0, 0)
#pragma unroll 1
  for (int ii = 0; ii < 9; ++ii) {
    __syncthreads();                    // wt[ih][ii&1] ready; prev reads done
    const int cur = ii & 1;
    if (ii < 8) STAGE(i0 + ii + 1, cur ^ 1)

    const int i = i0 + ii;
    const float* xp = x + ((size_t)b * II + i) * 8;
    const float4 x0 = *(const float4*)(xp);
    const float4 x1 = *(const float4*)(xp + 4);

    float xh[OO][2];
    float t[OO];
    const float* wtb = wt[ih][cur];
#pragma unroll 2
    for (int o = 0; o < OO; ++o) {
      const float4* wp = (const float4*)(wtb + (o * 8 + dsub) * PCH);
      const float4 wa = wp[0], wb2 = wp[1], wc = wp[2], wd = wp[3];
      xh[o][0] = wa.x * x0.x + wa.y * x0.y + wa.z * x0.z + wa.w * x0.w
               + wb2.x * x1.x + wb2.y * x1.y + wb2.z * x1.z + wb2.w * x1.w;
      xh[o][1] = wc.x * x0.x + wc.y * x0.y + wc.z * x0.z + wc.w * x0.w
               + wd.x * x1.x + wd.y * x1.y + wd.z * x1.z + wd.w * x1.w;
      if (K >= 1)
        t[o] = Vr[o][0] * xh[o][0] + Vr[o][1] * xh[o][1];
    }

    if (K == 0) {
#pragma unroll
      for (int o = 0; o < OO; ++o) { s[o][0] += xh[o][0]; s[o][1] += xh[o][1]; }
    } else {
#pragma unroll
      for (int o = 0; o < OO; ++o) {     // reduce over the 8 dsub lanes
        t[o] = dpp_add_xor1(t[o]);       // VALU pipe
        t[o] = dpp_add_xor2(t[o]);       // VALU pipe
        t[o] = swz_add_xor4(t[o]);       // DS pipe (only 10/iter now)
      }
      float sum = 0.f;
#pragma unroll
      for (int o = 0; o < OO; ++o) { t[o] = __expf(t[o]); sum += t[o]; }
      const float inv = __builtin_amdgcn_rcpf(sum);  // |t|<1 pre-exp; 1-ulp ok
#pragma unroll
      for (int o = 0; o < OO; ++o) {
        const float c = t[o] * inv;
        s[o][0] += c * xh[o][0];
        s[o][1] += c * xh[o][1];
      }
    }
  }

  if (K == 0) {
#pragma unroll
    for (int o = 0; o < OO; ++o) { s[o][0] *= 0.1f; s[o][1] *= 0.1f; }
  }

  // cross-i-half reduce: ih=1 parks s in LDS; ih=0 adds and atomically
  // accumulates into the global plane (single plane, NIB-free).
  if (ih == 1) {
#pragma unroll
    for (int o = 0; o < OO; ++o) {
      red[bh * 8 + bl][o * 16 + dsub * 2]     = s[o][0];
      red[bh * 8 + bl][o * 16 + dsub * 2 + 1] = s[o][1];
    }
  }
  __syncthreads();
  if (ih == 0) {
    float* out = plane + (size_t)b * (OO * DOUT);
    const float* rr = red[bh * 8 + bl];
#pragma unroll
    for (int o = 0; o < OO; ++o) {
      unsafeAtomicAdd(&out[o * 16 + dsub * 2],     s[o][0] + rr[o * 16 + dsub * 2]);
      unsafeAtomicAdd(&out[o * 16 + dsub * 2 + 1], s[o][1] + rr[o * 16 + dsub * 2 + 1]);
    }
  }
}

// Squash the accumulated plane, update V / write final output.
template<int K>
__global__ __launch_bounds__(256) void reduce_kernel(
    const float* __restrict__ plane,   // [B*O*DOUT]
    float* __restrict__ V,             // [B*O*DOUT]
    float* __restrict__ out)           // fp32 [B*O*DOUT]
{
  const int idx = blockIdx.x * 256 + threadIdx.x;    // over B*O*DOUT = 40960
  const float s = plane[idx];

  // squash over the 16 Dout lanes (contiguous 16-lane groups share (b,o))
  float sq = s * s;
  sq += __shfl_xor(sq, 1);
  sq += __shfl_xor(sq, 2);
  sq += __shfl_xor(sq, 4);
  sq += __shfl_xor(sq, 8);
  const float mag = sqrtf(sq);
  const float v = sq / (1.f + sq) * (s / (mag + 1e-8f));

  if (K == 0)      V[idx] = v;
  else if (K == 1) V[idx] += v;
  else             out[idx] = v;
}

extern "C" void kernel_launch(void* const* d_in, const int* in_sizes, int n_in,
                              void* d_out, int out_size, void* d_ws, size_t ws_size,
                              hipStream_t stream) {
  const float* x = (const float*)d_in[0];   // fp32 [256,1152,8]
  const float* w = (const float*)d_in[1];   // fp32 [10,1152,16,8]
  float* out = (float*)d_out;               // fp32 [256,10,16]

  const size_t P = (size_t)BB * OO * DOUT;  // 40960 floats per plane
  float* s0 = (float*)d_ws;                 // 3 accumulator planes + V
  float* s1 = s0 + P;
  float* s2 = s1 + P;
  float* V  = s2 + P;

  hipMemsetAsync(s0, 0, 3 * P * sizeof(float), stream);  // zero the 3 planes

  const int pg = 1024;                      // 64 ic (fast) x 16 bg; 4 blocks/CU
  const int rg = (int)(P / 256);            // 160 blocks

  pass_kernel<0><<<pg, 256, 0, stream>>>(x, w, V, s0);
  reduce_kernel<0><<<rg, 256, 0, stream>>>(s0, V, out);
  pass_kernel<1><<<pg, 256, 0, stream>>>(x, w, V, s1);
  reduce_kernel<1><<<rg, 256, 0, stream>>>(s1, V, out);
  pass_kernel<2><<<pg, 256, 0, stream>>>(x, w, V, s2);
  reduce_kernel<2><<<rg, 256, 0, stream>>>(s2, V, out);
}

// Round 12
// 203.183 us; speedup vs baseline: 1.1350x; 1.1164x over previous
//
#include <hip/hip_runtime.h>
#include <hip/hip_bf16.h>

#define BB   256
#define II   1152
#define OO   10
#define DOUT 16
#define PCH  20        // LDS chunk stride per (o,dsub): dsub*20 mod 32 -> conflict-free b128 reads

// Cross-lane reduce: xor1/xor2 on the VALU pipe (DPP quad_perm), xor4 on DS.
__device__ __forceinline__ float dpp_add_xor1(float v) {
  int r = __builtin_amdgcn_mov_dpp(__float_as_int(v), 0xB1, 0xF, 0xF, true);
  return v + __int_as_float(r);
}
__device__ __forceinline__ float dpp_add_xor2(float v) {
  int r = __builtin_amdgcn_mov_dpp(__float_as_int(v), 0x4E, 0xF, 0xF, true);
  return v + __int_as_float(r);
}
__device__ __forceinline__ float swz_add_xor4(float v) {
  int r = __builtin_amdgcn_ds_swizzle(__float_as_int(v), 0x101F);
  return v + __int_as_float(r);
}

// Pass kernel (R9 skeleton + R11 DPP/atomics): w staged global->LDS (float2),
// conflict-free broadcast reads. Lane = bl*8 + dsub (batch, d-pair).
// Block = 4 waves = 2 bh x 2 ih over 16 batches x 18 i. 64 ic x 16 bg = 1024
// blocks; ic fast-varying => XCD-local w. launch_bounds(256,3): empirically
// the allocator gives ~76-90 VGPR with NO spill (256,4 -> 64 VGPR + 40 MB
// scratch, R10/R11); 4 blocks/CU still resident since VGPR<=128, LDS 145<160K.
template<int K>
__global__ __launch_bounds__(256, 3) void pass_kernel(
    const float* __restrict__ x,     // fp32 [B][I][8]
    const float* __restrict__ w,     // fp32 [O][I][16][8]
    const float* __restrict__ V,     // fp32 [B][O][16]
    float* __restrict__ plane)       // fp32 [B][O][16] accumulator (pre-zeroed)
{
  const int tid  = threadIdx.x;
  const int lane = tid & 63;
  const int wv   = tid >> 6;
  const int bh   = wv & 1;             // b-half of the block's 16 batches
  const int ih   = wv >> 1;            // i-half (9 i each)
  const int dsub = lane & 7;           // d-pair index (d = 2*dsub + dlo)
  const int bl   = lane >> 3;          // batch-in-wave (8)
  const int ic   = blockIdx.x & 63;    // i-chunk (18 i), fast => XCD-local w
  const int bg   = blockIdx.x >> 6;    // 16 batches per block
  const int b    = bg * 16 + bh * 8 + bl;
  const int i0   = ic * 18 + ih * 9;

  __shared__ float wt[2][2][OO * 8 * PCH];   // [ih][buf][1600] = 25.6 KB
  __shared__ float red[16][168];             // cross-ih reduce, padded rows

  float Vr[OO][2];
  if (K >= 1) {
#pragma unroll
    for (int o = 0; o < OO; ++o) {
      const float2 v2 = *(const float2*)(V + (b * OO + o) * DOUT + dsub * 2);
      Vr[o][0] = v2.x; Vr[o][1] = v2.y;
    }
  }

  float s[OO][2];
#pragma unroll
  for (int o = 0; o < OO; ++o) { s[o][0] = 0.f; s[o][1] = 0.f; }

  // staging: 128 lanes (this i-half's wave pair) load w row i (1280 floats)
  // as float2: per 2-o group one coalesced 512 B load per wave.
  const int p    = bh * 64 + lane;       // 0..127
  const int so   = p >> 6;               // o parity (== bh)
  const int idx2 = (p & 63) * 2;         // even element within o-row
  const int sds  = idx2 >> 4;            // dsub 0..7
  const int ssk  = idx2 & 15;            // 0,2,..,14

  #define STAGE(i, buf)                                                        \
    {                                                                          \
      _Pragma("unroll")                                                        \
      for (int og = 0; og < 5; ++og) {                                         \
        const int o = og * 2 + so;                                             \
        const float2 v2 = *(const float2*)(w + ((size_t)o * II + (i)) * 128 + idx2); \
        *(float2*)&wt[ih][buf][(o * 8 + sds) * PCH + ssk] = v2;                \
      }                                                                        \
    }

  STAGE(i0, 0)
#pragma unroll 1
  for (int ii = 0; ii < 9; ++ii) {
    __syncthreads();                    // wt[ih][ii&1] ready; prev reads done
    const int cur = ii & 1;
    if (ii < 8) STAGE(i0 + ii + 1, cur ^ 1)

    const int i = i0 + ii;
    const float* xp = x + ((size_t)b * II + i) * 8;
    const float4 x0 = *(const float4*)(xp);
    const float4 x1 = *(const float4*)(xp + 4);

    float xh[OO][2];
    float t[OO];
    const float* wtb = wt[ih][cur];
#pragma unroll 2
    for (int o = 0; o < OO; ++o) {
      const float4* wp = (const float4*)(wtb + (o * 8 + dsub) * PCH);
      const float4 wa = wp[0], wb2 = wp[1], wc = wp[2], wd = wp[3];
      xh[o][0] = wa.x * x0.x + wa.y * x0.y + wa.z * x0.z + wa.w * x0.w
               + wb2.x * x1.x + wb2.y * x1.y + wb2.z * x1.z + wb2.w * x1.w;
      xh[o][1] = wc.x * x0.x + wc.y * x0.y + wc.z * x0.z + wc.w * x0.w
               + wd.x * x1.x + wd.y * x1.y + wd.z * x1.z + wd.w * x1.w;
      if (K >= 1)
        t[o] = Vr[o][0] * xh[o][0] + Vr[o][1] * xh[o][1];
    }

    if (K == 0) {
#pragma unroll
      for (int o = 0; o < OO; ++o) { s[o][0] += xh[o][0]; s[o][1] += xh[o][1]; }
    } else {
#pragma unroll
      for (int o = 0; o < OO; ++o) {     // reduce over the 8 dsub lanes
        t[o] = dpp_add_xor1(t[o]);       // VALU pipe
        t[o] = dpp_add_xor2(t[o]);       // VALU pipe
        t[o] = swz_add_xor4(t[o]);       // DS pipe (10/iter)
      }
      float sum = 0.f;
#pragma unroll
      for (int o = 0; o < OO; ++o) { t[o] = __expf(t[o]); sum += t[o]; }
      const float inv = __builtin_amdgcn_rcpf(sum);  // |t|<1 pre-exp; 1-ulp ok
#pragma unroll
      for (int o = 0; o < OO; ++o) {
        const float c = t[o] * inv;
        s[o][0] += c * xh[o][0];
        s[o][1] += c * xh[o][1];
      }
    }
  }

  if (K == 0) {
#pragma unroll
    for (int o = 0; o < OO; ++o) { s[o][0] *= 0.1f; s[o][1] *= 0.1f; }
  }

  // cross-i-half reduce: ih=1 parks s in LDS; ih=0 adds and atomically
  // accumulates into the single global plane.
  if (ih == 1) {
#pragma unroll
    for (int o = 0; o < OO; ++o) {
      red[bh * 8 + bl][o * 16 + dsub * 2]     = s[o][0];
      red[bh * 8 + bl][o * 16 + dsub * 2 + 1] = s[o][1];
    }
  }
  __syncthreads();
  if (ih == 0) {
    float* out = plane + (size_t)b * (OO * DOUT);
    const float* rr = red[bh * 8 + bl];
#pragma unroll
    for (int o = 0; o < OO; ++o) {
      unsafeAtomicAdd(&out[o * 16 + dsub * 2],     s[o][0] + rr[o * 16 + dsub * 2]);
      unsafeAtomicAdd(&out[o * 16 + dsub * 2 + 1], s[o][1] + rr[o * 16 + dsub * 2 + 1]);
    }
  }
}

// Squash the accumulated plane, update V / write final output.
template<int K>
__global__ __launch_bounds__(256) void reduce_kernel(
    const float* __restrict__ plane,   // [B*O*DOUT]
    float* __restrict__ V,             // [B*O*DOUT]
    float* __restrict__ out)           // fp32 [B*O*DOUT]
{
  const int idx = blockIdx.x * 256 + threadIdx.x;    // over B*O*DOUT = 40960
  const float s = plane[idx];

  // squash over the 16 Dout lanes (contiguous 16-lane groups share (b,o))
  float sq = s * s;
  sq += __shfl_xor(sq, 1);
  sq += __shfl_xor(sq, 2);
  sq += __shfl_xor(sq, 4);
  sq += __shfl_xor(sq, 8);
  const float mag = sqrtf(sq);
  const float v = sq / (1.f + sq) * (s / (mag + 1e-8f));

  if (K == 0)      V[idx] = v;
  else if (K == 1) V[idx] += v;
  else             out[idx] = v;
}

extern "C" void kernel_launch(void* const* d_in, const int* in_sizes, int n_in,
                              void* d_out, int out_size, void* d_ws, size_t ws_size,
                              hipStream_t stream) {
  const float* x = (const float*)d_in[0];   // fp32 [256,1152,8]
  const float* w = (const float*)d_in[1];   // fp32 [10,1152,16,8]
  float* out = (float*)d_out;               // fp32 [256,10,16]

  const size_t P = (size_t)BB * OO * DOUT;  // 40960 floats per plane
  float* s0 = (float*)d_ws;                 // 3 accumulator planes + V
  float* s1 = s0 + P;
  float* s2 = s1 + P;
  float* V  = s2 + P;

  hipMemsetAsync(s0, 0, 3 * P * sizeof(float), stream);  // zero the 3 planes

  const int pg = 1024;                      // 64 ic (fast) x 16 bg; 4 blocks/CU
  const int rg = (int)(P / 256);            // 160 blocks

  pass_kernel<0><<<pg, 256, 0, stream>>>(x, w, V, s0);
  reduce_kernel<0><<<rg, 256, 0, stream>>>(s0, V, out);
  pass_kernel<1><<<pg, 256, 0, stream>>>(x, w, V, s1);
  reduce_kernel<1><<<rg, 256, 0, stream>>>(s1, V, out);
  pass_kernel<2><<<pg, 256, 0, stream>>>(x, w, V, s2);
  reduce_kernel<2><<<rg, 256, 0, stream>>>(s2, V, out);
}

// Round 13
// 185.213 us; speedup vs baseline: 1.2451x; 1.0970x over previous
//
#include <hip/hip_runtime.h>
#include <hip/hip_bf16.h>

#define BB   256
#define II   1152
#define OO   10
#define DOUT 16
#define PCHH 24   // f16 stride per (o,dsub) chunk: 12 dwords -> dsub*12 mod 32 disjoint bank-quads

using h2 = __fp16 __attribute__((ext_vector_type(2)));
using h8 = __fp16 __attribute__((ext_vector_type(8)));
#define H2V(v, a, b) __builtin_shufflevector((v), (v), (a), (b))
#define FD(a, b, c)  __builtin_amdgcn_fdot2((a), (b), (c), false)   // v_dot2_f32_f16: f32 accumulate

// Cross-lane reduce: xor1/xor2 on the VALU pipe (DPP quad_perm), xor4 on DS.
__device__ __forceinline__ float dpp_add_xor1(float v) {
  int r = __builtin_amdgcn_mov_dpp(__float_as_int(v), 0xB1, 0xF, 0xF, true);
  return v + __int_as_float(r);
}
__device__ __forceinline__ float dpp_add_xor2(float v) {
  int r = __builtin_amdgcn_mov_dpp(__float_as_int(v), 0x4E, 0xF, 0xF, true);
  return v + __int_as_float(r);
}
__device__ __forceinline__ float swz_add_xor4(float v) {
  int r = __builtin_amdgcn_ds_swizzle(__float_as_int(v), 0x101F);
  return v + __int_as_float(r);
}

// Pass kernel (R12 skeleton, f16 LDS + dot2): w staged global->LDS with
// cvt_pkrtz to f16 (halves DS-read issue: 20 b128/wave-iter instead of 40,
// the R12-measured binder), xh computed with v_dot2_f32_f16 (halves FMA
// count, f32 accumulate -> no f16 accumulation error). Lane = bl*8 + dsub.
// Block = 4 waves = 2 bh x 2 ih over 16 batches x 18 i. 64 ic x 16 bg = 1024
// blocks; ic fast-varying => XCD-local w. launch_bounds(256,3): proven
// allocator sweet spot (R12: 72 VGPR, no spill).
template<int K>
__global__ __launch_bounds__(256, 3) void pass_kernel(
    const float* __restrict__ x,     // fp32 [B][I][8]
    const float* __restrict__ w,     // fp32 [O][I][16][8]
    const float* __restrict__ V,     // fp32 [B][O][16]
    float* __restrict__ plane)       // fp32 [B][O][16] accumulator (pre-zeroed)
{
  const int tid  = threadIdx.x;
  const int lane = tid & 63;
  const int wv   = tid >> 6;
  const int bh   = wv & 1;             // b-half of the block's 16 batches
  const int ih   = wv >> 1;            // i-half (9 i each)
  const int dsub = lane & 7;           // d-pair index (d = 2*dsub + dlo)
  const int bl   = lane >> 3;          // batch-in-wave (8)
  const int ic   = blockIdx.x & 63;    // i-chunk (18 i), fast => XCD-local w
  const int bg   = blockIdx.x >> 6;    // 16 batches per block
  const int b    = bg * 16 + bh * 8 + bl;
  const int i0   = ic * 18 + ih * 9;

  __shared__ __fp16 wt[2][2][OO * 8 * PCHH];   // f16 tiles: 15.4 KB total
  __shared__ float red[16][168];               // cross-ih reduce, padded rows

  float Vr[OO][2];
  if (K >= 1) {
#pragma unroll
    for (int o = 0; o < OO; ++o) {
      const float2 v2 = *(const float2*)(V + (b * OO + o) * DOUT + dsub * 2);
      Vr[o][0] = v2.x; Vr[o][1] = v2.y;
    }
  }

  float s[OO][2];
#pragma unroll
  for (int o = 0; o < OO; ++o) { s[o][0] = 0.f; s[o][1] = 0.f; }

  // staging: 128 lanes load w row i (1280 floats) as float2, convert to h2
  // (cvt_pkrtz), store b32. Write banks <=2-way aliased (free).
  const int p    = bh * 64 + lane;       // 0..127
  const int so   = p >> 6;               // o parity (== bh)
  const int idx2 = (p & 63) * 2;         // even element within o-row
  const int sds  = idx2 >> 4;            // dsub 0..7
  const int ssk  = idx2 & 15;            // 0,2,..,14

  #define STAGE(i, buf)                                                        \
    {                                                                          \
      _Pragma("unroll")                                                        \
      for (int og = 0; og < 5; ++og) {                                         \
        const int o = og * 2 + so;                                             \
        const float2 v2 = *(const float2*)(w + ((size_t)o * II + (i)) * 128 + idx2); \
        *(h2*)&wt[ih][buf][(o * 8 + sds) * PCHH + ssk] =                       \
            __builtin_amdgcn_cvt_pkrtz(v2.x, v2.y);                            \
      }                                                                        \
    }

  STAGE(i0, 0)
#pragma unroll 1
  for (int ii = 0; ii < 9; ++ii) {
    __syncthreads();                    // wt[ih][ii&1] ready; prev reads done
    const int cur = ii & 1;
    if (ii < 8) STAGE(i0 + ii + 1, cur ^ 1)

    const int i = i0 + ii;
    const float* xp = x + ((size_t)b * II + i) * 8;
    const float4 x0 = *(const float4*)(xp);
    const float4 x1 = *(const float4*)(xp + 4);
    const h2 xq0 = __builtin_amdgcn_cvt_pkrtz(x0.x, x0.y);
    const h2 xq1 = __builtin_amdgcn_cvt_pkrtz(x0.z, x0.w);
    const h2 xq2 = __builtin_amdgcn_cvt_pkrtz(x1.x, x1.y);
    const h2 xq3 = __builtin_amdgcn_cvt_pkrtz(x1.z, x1.w);

    float xh[OO][2];
    float t[OO];
    const __fp16* wtb = wt[ih][cur];
#pragma unroll 2
    for (int o = 0; o < OO; ++o) {
      const __fp16* cp = wtb + (o * 8 + dsub) * PCHH;   // 48 B-aligned
      const h8 wa = *(const h8*)(cp);                   // d even: 8 c's
      const h8 wb = *(const h8*)(cp + 8);               // d odd:  8 c's
      xh[o][0] = FD(H2V(wa, 0, 1), xq0, FD(H2V(wa, 2, 3), xq1,
                 FD(H2V(wa, 4, 5), xq2, FD(H2V(wa, 6, 7), xq3, 0.f))));
      xh[o][1] = FD(H2V(wb, 0, 1), xq0, FD(H2V(wb, 2, 3), xq1,
                 FD(H2V(wb, 4, 5), xq2, FD(H2V(wb, 6, 7), xq3, 0.f))));
      if (K >= 1)
        t[o] = Vr[o][0] * xh[o][0] + Vr[o][1] * xh[o][1];
    }

    if (K == 0) {
#pragma unroll
      for (int o = 0; o < OO; ++o) { s[o][0] += xh[o][0]; s[o][1] += xh[o][1]; }
    } else {
#pragma unroll
      for (int o = 0; o < OO; ++o) {     // reduce over the 8 dsub lanes
        t[o] = dpp_add_xor1(t[o]);       // VALU pipe
        t[o] = dpp_add_xor2(t[o]);       // VALU pipe
        t[o] = swz_add_xor4(t[o]);       // DS pipe (10/iter)
      }
      float sum = 0.f;
#pragma unroll
      for (int o = 0; o < OO; ++o) { t[o] = __expf(t[o]); sum += t[o]; }
      const float inv = __builtin_amdgcn_rcpf(sum);  // |t|<1 pre-exp; 1-ulp ok
#pragma unroll
      for (int o = 0; o < OO; ++o) {
        const float c = t[o] * inv;
        s[o][0] += c * xh[o][0];
        s[o][1] += c * xh[o][1];
      }
    }
  }

  if (K == 0) {
#pragma unroll
    for (int o = 0; o < OO; ++o) { s[o][0] *= 0.1f; s[o][1] *= 0.1f; }
  }

  // cross-i-half reduce: ih=1 parks s in LDS; ih=0 adds and atomically
  // accumulates into the single global plane.
  if (ih == 1) {
#pragma unroll
    for (int o = 0; o < OO; ++o) {
      red[bh * 8 + bl][o * 16 + dsub * 2]     = s[o][0];
      red[bh * 8 + bl][o * 16 + dsub * 2 + 1] = s[o][1];
    }
  }
  __syncthreads();
  if (ih == 0) {
    float* out = plane + (size_t)b * (OO * DOUT);
    const float* rr = red[bh * 8 + bl];
#pragma unroll
    for (int o = 0; o < OO; ++o) {
      unsafeAtomicAdd(&out[o * 16 + dsub * 2],     s[o][0] + rr[o * 16 + dsub * 2]);
      unsafeAtomicAdd(&out[o * 16 + dsub * 2 + 1], s[o][1] + rr[o * 16 + dsub * 2 + 1]);
    }
  }
}

// Squash the accumulated plane, update V / write final output.
template<int K>
__global__ __launch_bounds__(256) void reduce_kernel(
    const float* __restrict__ plane,   // [B*O*DOUT]
    float* __restrict__ V,             // [B*O*DOUT]
    float* __restrict__ out)           // fp32 [B*O*DOUT]
{
  const int idx = blockIdx.x * 256 + threadIdx.x;    // over B*O*DOUT = 40960
  const float s = plane[idx];

  // squash over the 16 Dout lanes (contiguous 16-lane groups share (b,o))
  float sq = s * s;
  sq += __shfl_xor(sq, 1);
  sq += __shfl_xor(sq, 2);
  sq += __shfl_xor(sq, 4);
  sq += __shfl_xor(sq, 8);
  const float mag = sqrtf(sq);
  const float v = sq / (1.f + sq) * (s / (mag + 1e-8f));

  if (K == 0)      V[idx] = v;
  else if (K == 1) V[idx] += v;
  else             out[idx] = v;
}

extern "C" void kernel_launch(void* const* d_in, const int* in_sizes, int n_in,
                              void* d_out, int out_size, void* d_ws, size_t ws_size,
                              hipStream_t stream) {
  const float* x = (const float*)d_in[0];   // fp32 [256,1152,8]
  const float* w = (const float*)d_in[1];   // fp32 [10,1152,16,8]
  float* out = (float*)d_out;               // fp32 [256,10,16]

  const size_t P = (size_t)BB * OO * DOUT;  // 40960 floats per plane
  float* s0 = (float*)d_ws;                 // 3 accumulator planes + V
  float* s1 = s0 + P;
  float* s2 = s1 + P;
  float* V  = s2 + P;

  hipMemsetAsync(s0, 0, 3 * P * sizeof(float), stream);  // zero the 3 planes

  const int pg = 1024;                      // 64 ic (fast) x 16 bg; 4 blocks/CU
  const int rg = (int)(P / 256);            // 160 blocks

  pass_kernel<0><<<pg, 256, 0, stream>>>(x, w, V, s0);
  reduce_kernel<0><<<rg, 256, 0, stream>>>(s0, V, out);
  pass_kernel<1><<<pg, 256, 0, stream>>>(x, w, V, s1);
  reduce_kernel<1><<<rg, 256, 0, stream>>>(s1, V, out);
  pass_kernel<2><<<pg, 256, 0, stream>>>(x, w, V, s2);
  reduce_kernel<2><<<rg, 256, 0, stream>>>(s2, V, out);
}